// Round 7
// baseline (22.414 us; speedup 1.0000x reference)
//
#include <hip/hip_runtime.h>
#include <hip/hip_fp16.h>

// Problem constants (match reference)
#define BATCH 32
#define CH    2
#define HH    224
#define WW    224
#define PP    4096
#define NN    256
#define SPLIT 16
#define TILE  (PP / SPLIT)   // 256 points per block
#define TILE2 (TILE / 2)     // 128 packed point-pairs

// ws layout: [0,64K) float2 Y[B*N]; [64K,80K) part[512*4] dbl;
// [80K,84K) uint cnt[32 batches * 32-uint stride (128B lines)].
#define WS_Y_OFF    0
#define WS_PART_OFF (64 * 1024)
#define WS_CNT_OFF  (80 * 1024)
#define WS_NEED     (84 * 1024)
#define CNT_STRIDE  32          // uints; one 128B cache line per batch

// Packed vote-point pair: (u0,u1),(v0,v1),(-c0,-c1) in f16, padded to 16B so
// the vote loop reads one ds_read_b128 (broadcast) per TWO points.
// c = py*u + px*v, so agree = sign(yy*u + yx*v - c)  (the reference's
// normalization can't flip the sign, so the norm is dropped).
struct alignas(16) PtPack { __half2 u, v, nc, pad; };

// ---- shared solve: 2x2 pinv (f64, matches jnp.linalg.pinv semantics) ----
__device__ inline float2 solve_pair(const float* __restrict__ uvb,
                                    const int* __restrict__ ptsb,
                                    const int* __restrict__ pairb, int n)
{
    const int2 pr = *(const int2*)(pairb + n * 2);
    const int2 p0 = *(const int2*)(ptsb + pr.x * 2);
    const int2 p1 = *(const int2*)(ptsb + pr.y * 2);
    const int y0 = p0.x, x0 = p0.y;
    const int y1 = p1.x, x1 = p1.y;

    const float u0a = uvb[y0 * WW + x0];                 // uv[0] at pt0
    const float u0b = uvb[HH * WW + y0 * WW + x0];       // uv[1] at pt0
    const float u1a = uvb[y1 * WW + x1];                 // uv[0] at pt1
    const float u1b = uvb[HH * WW + y1 * WW + x1];       // uv[1] at pt1

    const double a00 = (double)u0a, a01 = -(double)u1a;
    const double a10 = (double)u0b, a11 = -(double)u1b;
    const double b0 = (double)(y1 - y0), b1 = (double)(x1 - x0);
    const double det = a00 * a11 - a01 * a10;
    const double frob2 = a00 * a00 + a01 * a01 + a10 * a10 + a11 * a11;

    double t0;
    if (fabs(det) > 1e-12 * frob2) {
        t0 = (b0 * a11 - b1 * a01) / det;          // first row of A^{-1} b
    } else if (frob2 > 0.0) {
        t0 = (a00 * b0 + a10 * b1) / frob2;        // rank-1 pinv: A^T b / ||A||_F^2
    } else {
        t0 = 0.0;
    }
    return make_float2((float)(t0 * (double)u0a + (double)y0),   // row
                       (float)(t0 * (double)u0b + (double)x0));  // col
}

// Kernel 1: solve every (b,n) ONCE, spread over 128 CUs (128 blocks x 64
// threads) to shorten the dependent-gather latency chain. Block 0 also
// zeroes the per-batch completion counters (stream order => visible to K2).
__global__ __launch_bounds__(64)
void hough_solve(const float* __restrict__ uv,
                 const int* __restrict__ pts,
                 const int* __restrict__ pair,
                 float2* __restrict__ yv,
                 unsigned* __restrict__ cnt)
{
    const int blk = blockIdx.x;          // 128 blocks: 4 per batch
    const int b = blk >> 2;
    const int n = ((blk & 3) << 6) + threadIdx.x;
    const float* uvb = uv + (size_t)b * CH * HH * WW;
    yv[b * NN + n] = solve_pair(uvb, pts + b * PP * 2, pair + b * NN * 2, n);
    if (blk == 0 && threadIdx.x < BATCH)
        __hip_atomic_store(&cnt[threadIdx.x * CNT_STRIDE], 0u,
                           __ATOMIC_RELAXED, __HIP_MEMORY_SCOPE_AGENT);
}

// Kernel 2: one block per (batch, point-tile). 256 threads, one per pair n.
//   1. stage TILE points as f16 PtPacks in LDS
//   2. read Y (coalesced 8B), rescale into f16-safe range
//   3. packed-f16 vote, sign-bit counting
//   4. wave-shuffle reduce -> per-block partial, published via RELAXED
//      agent-scope atomic stores ordered by a RELEASE fetch_add on the
//      per-batch counter (separate cache line per batch -> 32 parallel
//      chains of 16 RMWs, no threadfence, no L2 writeback).
//   5. last block of each batch combines its 16 partials (fixed order).
__global__ __launch_bounds__(256, 4)
void hough_vote(const float* __restrict__ uv,
                const int* __restrict__ pts,
                const float2* __restrict__ yv,
                double* __restrict__ part,
                unsigned* __restrict__ cnt,
                float* __restrict__ out)
{
    const int blk = blockIdx.x;
    const int b = blk / SPLIT;
    const int s = blk % SPLIT;
    const int t = threadIdx.x;   // n = t

    const float* uvb = uv + (size_t)b * CH * HH * WW;
    const int* ptsb = pts + b * PP * 2;

    // ---- stage this block's point tile in LDS (f16-packed, 2 pts / 16B) ----
    __shared__ PtPack tile[TILE2];
    if (t < TILE2) {
        const int p = s * TILE + 2 * t;
        const int4 pp = *(const int4*)(ptsb + p * 2);   // (y0,x0,y1,x1), 16B
        const float u0 = uvb[pp.x * WW + pp.y];
        const float v0 = uvb[HH * WW + pp.x * WW + pp.y];
        const float u1 = uvb[pp.z * WW + pp.w];
        const float v1 = uvb[HH * WW + pp.z * WW + pp.w];
        const float c0 = (float)pp.x * u0 + (float)pp.y * v0;
        const float c1 = (float)pp.z * u1 + (float)pp.w * v1;
        PtPack pk;
        pk.u  = __floats2half2_rn(u0, u1);
        pk.v  = __floats2half2_rn(v0, v1);
        pk.nc = __floats2half2_rn(-c0, -c1);
        pk.pad = __floats2half2_rn(0.0f, 0.0f);
        tile[t] = pk;
    }

    // ---- read precomputed Y, scale (yy, yx, 1) into f16-safe range ----
    const float2 Yn = yv[b * NN + t];
    const float yy = Yn.x, yx = Yn.y;
    const float maxab = fmaxf(fabsf(yy), fabsf(yx));
    const float sc = (maxab > 1024.0f) ? (1024.0f / maxab) : 1.0f;
    const __half2 yy2 = __float2half2_rn(yy * sc);
    const __half2 yx2 = __float2half2_rn(yx * sc);
    const __half2 sc2 = __float2half2_rn(sc);

    __syncthreads();

    // ---- voting: packed f16, 2 points per iteration, sign-bit counting ----
    unsigned negs = 0u;
    #pragma unroll 8
    for (int j = 0; j < TILE2; ++j) {
        const PtPack q = tile[j];                  // broadcast ds_read_b128
        __half2 d = __hmul2(yy2, q.u);
        d = __hfma2(yx2, q.v, d);
        d = __hfma2(sc2, q.nc, d);
        unsigned ub;
        __builtin_memcpy(&ub, &d, 4);
        negs += (ub >> 15) & 0x00010001u;          // sign bits of both halves
    }
    const int cw = TILE - (int)(negs & 0xFFFFu) - (int)(negs >> 16);

    // ---- deterministic reduction of (w*Yy, w*Yx, w) ----
    double wy = (double)cw * (double)yy;
    double wx = (double)cw * (double)yx;
    double ww = (double)cw;
    #pragma unroll
    for (int off = 32; off > 0; off >>= 1) {
        wy += __shfl_down(wy, off);
        wx += __shfl_down(wx, off);
        ww += __shfl_down(ww, off);
    }

    __shared__ double red[4 * 3];
    __shared__ int lastFlag;
    const int wid = t >> 6;
    if ((t & 63) == 0) {
        red[wid * 3 + 0] = wy;
        red[wid * 3 + 1] = wx;
        red[wid * 3 + 2] = ww;
    }
    __syncthreads();
    if (t == 0) {
        double* o = part + (size_t)blk * 4;
        __hip_atomic_store(&o[0], red[0] + red[3] + red[6] + red[9],
                           __ATOMIC_RELAXED, __HIP_MEMORY_SCOPE_AGENT);
        __hip_atomic_store(&o[1], red[1] + red[4] + red[7] + red[10],
                           __ATOMIC_RELAXED, __HIP_MEMORY_SCOPE_AGENT);
        __hip_atomic_store(&o[2], red[2] + red[5] + red[8] + red[11],
                           __ATOMIC_RELAXED, __HIP_MEMORY_SCOPE_AGENT);
        // RELEASE orders the partial stores before the increment.
        const unsigned prev = __hip_atomic_fetch_add(
            &cnt[b * CNT_STRIDE], 1u, __ATOMIC_RELEASE,
            __HIP_MEMORY_SCOPE_AGENT);
        lastFlag = (prev == SPLIT - 1);
    }
    __syncthreads();

    // ---- last block of this batch combines (fixed order => deterministic) --
    if (lastFlag && t < SPLIT) {
        // ACQUIRE pairs with the producers' RELEASE increments.
        if (t == 0)
            (void)__hip_atomic_load(&cnt[b * CNT_STRIDE],
                                    __ATOMIC_ACQUIRE, __HIP_MEMORY_SCOPE_AGENT);
        const double* o = part + (size_t)(b * SPLIT + t) * 4;
        double sy = __hip_atomic_load(&o[0], __ATOMIC_RELAXED, __HIP_MEMORY_SCOPE_AGENT);
        double sx = __hip_atomic_load(&o[1], __ATOMIC_RELAXED, __HIP_MEMORY_SCOPE_AGENT);
        double sw = __hip_atomic_load(&o[2], __ATOMIC_RELAXED, __HIP_MEMORY_SCOPE_AGENT);
        #pragma unroll
        for (int off = 1; off < SPLIT; off <<= 1) {
            sy += __shfl_xor(sy, off, SPLIT);
            sx += __shfl_xor(sx, off, SPLIT);
            sw += __shfl_xor(sw, off, SPLIT);
        }
        if (t == 0) {
            // weighted_mean = (sy/sw, sx/sw) in (row, col); output is [::-1]
            out[b * 2 + 0] = (float)(sx / sw);
            out[b * 2 + 1] = (float)(sy / sw);
        }
    }
}

// ---------------- fallback (R6-proven 3-node shape), used if ws too small ---
__global__ __launch_bounds__(256, 4)
void hough_vote_nb(const float* __restrict__ uv,
                   const int* __restrict__ pts,
                   const float2* __restrict__ yv,
                   double* __restrict__ part)
{
    const int blk = blockIdx.x;
    const int b = blk / SPLIT;
    const int s = blk % SPLIT;
    const int t = threadIdx.x;

    const float* uvb = uv + (size_t)b * CH * HH * WW;
    const int* ptsb = pts + b * PP * 2;

    __shared__ PtPack tile[TILE2];
    if (t < TILE2) {
        const int p = s * TILE + 2 * t;
        const int4 pp = *(const int4*)(ptsb + p * 2);
        const float u0 = uvb[pp.x * WW + pp.y];
        const float v0 = uvb[HH * WW + pp.x * WW + pp.y];
        const float u1 = uvb[pp.z * WW + pp.w];
        const float v1 = uvb[HH * WW + pp.z * WW + pp.w];
        const float c0 = (float)pp.x * u0 + (float)pp.y * v0;
        const float c1 = (float)pp.z * u1 + (float)pp.w * v1;
        PtPack pk;
        pk.u  = __floats2half2_rn(u0, u1);
        pk.v  = __floats2half2_rn(v0, v1);
        pk.nc = __floats2half2_rn(-c0, -c1);
        pk.pad = __floats2half2_rn(0.0f, 0.0f);
        tile[t] = pk;
    }

    const float2 Yn = yv[b * NN + t];
    const float yy = Yn.x, yx = Yn.y;
    const float maxab = fmaxf(fabsf(yy), fabsf(yx));
    const float sc = (maxab > 1024.0f) ? (1024.0f / maxab) : 1.0f;
    const __half2 yy2 = __float2half2_rn(yy * sc);
    const __half2 yx2 = __float2half2_rn(yx * sc);
    const __half2 sc2 = __float2half2_rn(sc);

    __syncthreads();

    unsigned negs = 0u;
    #pragma unroll 8
    for (int j = 0; j < TILE2; ++j) {
        const PtPack q = tile[j];
        __half2 d = __hmul2(yy2, q.u);
        d = __hfma2(yx2, q.v, d);
        d = __hfma2(sc2, q.nc, d);
        unsigned ub;
        __builtin_memcpy(&ub, &d, 4);
        negs += (ub >> 15) & 0x00010001u;
    }
    const int cw = TILE - (int)(negs & 0xFFFFu) - (int)(negs >> 16);

    double wy = (double)cw * (double)yy;
    double wx = (double)cw * (double)yx;
    double ww = (double)cw;
    #pragma unroll
    for (int off = 32; off > 0; off >>= 1) {
        wy += __shfl_down(wy, off);
        wx += __shfl_down(wx, off);
        ww += __shfl_down(ww, off);
    }
    __shared__ double red[4 * 3];
    const int wid = t >> 6;
    if ((t & 63) == 0) {
        red[wid * 3 + 0] = wy;
        red[wid * 3 + 1] = wx;
        red[wid * 3 + 2] = ww;
    }
    __syncthreads();
    if (t == 0) {
        double* o = part + (size_t)blk * 4;
        o[0] = red[0] + red[3] + red[6] + red[9];
        o[1] = red[1] + red[4] + red[7] + red[10];
        o[2] = red[2] + red[5] + red[8] + red[11];
    }
}

__global__ __launch_bounds__(256)
void hough_final(const double* __restrict__ part, float* __restrict__ out)
{
    const int t = threadIdx.x;
    const int bb = t >> 3;
    const int l8 = t & 7;
    double sy = 0.0, sx = 0.0, sw = 0.0;
    #pragma unroll
    for (int k = l8; k < SPLIT; k += 8) {
        const double* o = part + (size_t)(bb * SPLIT + k) * 4;
        sy += o[0];
        sx += o[1];
        sw += o[2];
    }
    #pragma unroll
    for (int off = 1; off < 8; off <<= 1) {
        sy += __shfl_xor(sy, off);
        sx += __shfl_xor(sx, off);
        sw += __shfl_xor(sw, off);
    }
    if (l8 == 0) {
        out[bb * 2 + 0] = (float)(sx / sw);
        out[bb * 2 + 1] = (float)(sy / sw);
    }
}

extern "C" void kernel_launch(void* const* d_in, const int* in_sizes, int n_in,
                              void* d_out, int out_size, void* d_ws, size_t ws_size,
                              hipStream_t stream)
{
    const float* uv   = (const float*)d_in[0];   // (B, 2, 224, 224) f32
    const int*   pts  = (const int*)d_in[1];     // (B, 4096, 2) i32
    const int*   pair = (const int*)d_in[2];     // (B, 256, 2) i32
    float* out = (float*)d_out;                  // (B, 2) f32
    char* ws = (char*)d_ws;

    float2*   yv   = (float2*)(ws + WS_Y_OFF);
    double*   part = (double*)(ws + WS_PART_OFF);
    unsigned* cnt  = (unsigned*)(ws + WS_CNT_OFF);

    if (ws_size >= WS_NEED) {
        hough_solve<<<128, 64, 0, stream>>>(uv, pts, pair, yv, cnt);
        hough_vote<<<BATCH * SPLIT, 256, 0, stream>>>(uv, pts, yv, part, cnt, out);
    } else {
        // 3-node fence-free fallback (fits in 80 KB)
        hough_solve<<<128, 64, 0, stream>>>(uv, pts, pair, yv, cnt);
        hough_vote_nb<<<BATCH * SPLIT, 256, 0, stream>>>(uv, pts, yv, part);
        hough_final<<<1, 256, 0, stream>>>(part, out);
    }
}

// Round 8
// 19.907 us; speedup vs baseline: 1.1259x; 1.1259x over previous
//
#include <hip/hip_runtime.h>
#include <hip/hip_fp16.h>

// Problem constants (match reference)
#define BATCH 32
#define CH    2
#define HH    224
#define WW    224
#define PP    4096
#define NN    256
#define SPLIT 16
#define TILE  (PP / SPLIT)   // 256 points per block
#define TILE2 (TILE / 2)     // 128 packed point-pairs

// ws layout: [0,64K) float2 Y[B*N]; [64K,80K) part[512*4] dbl.
#define WS_Y_OFF    0
#define WS_PART_OFF (64 * 1024)
#define WS_NEED     (80 * 1024)

// Packed vote-point pair: (u0,u1),(v0,v1),(-c0,-c1) in f16, padded to 16B so
// the vote loop reads one ds_read_b128 (broadcast) per TWO points.
// c = py*u + px*v, so agree = sign(yy*u + yx*v - c)  (the reference's
// normalization can't flip the sign, so the norm is dropped).
struct alignas(16) PtPack { __half2 u, v, nc, pad; };

// ---- shared solve: 2x2 pinv (f64, matches jnp.linalg.pinv semantics) ----
__device__ inline float2 solve_pair(const float* __restrict__ uvb,
                                    const int* __restrict__ ptsb,
                                    const int* __restrict__ pairb, int n)
{
    const int2 pr = *(const int2*)(pairb + n * 2);
    const int2 p0 = *(const int2*)(ptsb + pr.x * 2);
    const int2 p1 = *(const int2*)(ptsb + pr.y * 2);
    const int y0 = p0.x, x0 = p0.y;
    const int y1 = p1.x, x1 = p1.y;

    const float u0a = uvb[y0 * WW + x0];                 // uv[0] at pt0
    const float u0b = uvb[HH * WW + y0 * WW + x0];       // uv[1] at pt0
    const float u1a = uvb[y1 * WW + x1];                 // uv[0] at pt1
    const float u1b = uvb[HH * WW + y1 * WW + x1];       // uv[1] at pt1

    const double a00 = (double)u0a, a01 = -(double)u1a;
    const double a10 = (double)u0b, a11 = -(double)u1b;
    const double b0 = (double)(y1 - y0), b1 = (double)(x1 - x0);
    const double det = a00 * a11 - a01 * a10;
    const double frob2 = a00 * a00 + a01 * a01 + a10 * a10 + a11 * a11;

    double t0;
    if (fabs(det) > 1e-12 * frob2) {
        t0 = (b0 * a11 - b1 * a01) / det;          // first row of A^{-1} b
    } else if (frob2 > 0.0) {
        t0 = (a00 * b0 + a10 * b1) / frob2;        // rank-1 pinv: A^T b / ||A||_F^2
    } else {
        t0 = 0.0;
    }
    return make_float2((float)(t0 * (double)u0a + (double)y0),   // row
                       (float)(t0 * (double)u0b + (double)x0));  // col
}

// Kernel 1: solve every (b,n) ONCE, 128 blocks x 64 threads (one item per
// thread, fully parallel 3-deep gather chain). No atomics, no fences.
__global__ __launch_bounds__(64)
void hough_solve(const float* __restrict__ uv,
                 const int* __restrict__ pts,
                 const int* __restrict__ pair,
                 float2* __restrict__ yv)
{
    const int blk = blockIdx.x;          // 128 blocks: 4 per batch
    const int b = blk >> 2;
    const int n = ((blk & 3) << 6) + threadIdx.x;
    const float* uvb = uv + (size_t)b * CH * HH * WW;
    yv[b * NN + n] = solve_pair(uvb, pts + b * PP * 2, pair + b * NN * 2, n);
}

// Kernel 2: one block per (batch, point-tile). 256 threads, one per pair n.
//   1. stage TILE=256 points: EVERY thread stages one point (2 scattered
//      gathers + 3 ds_write_b16 into the pack layout; 2-way bank alias free)
//   2. read Y (coalesced 8B), rescale into f16-safe range
//   3. packed-f16 vote over 128 packs, sign-bit counting
//   4. wave-shuffle reduce -> per-block partial. Nothing else.
__global__ __launch_bounds__(256, 4)
void hough_vote(const float* __restrict__ uv,
                const int* __restrict__ pts,
                const float2* __restrict__ yv,
                double* __restrict__ part)
{
    const int blk = blockIdx.x;
    const int b = blk / SPLIT;
    const int s = blk % SPLIT;
    const int t = threadIdx.x;   // n = t

    const float* uvb = uv + (size_t)b * CH * HH * WW;
    const int* ptsb = pts + b * PP * 2;

    // ---- stage: one point per thread into the f16 pack layout ----
    __shared__ PtPack tile[TILE2];
    {
        const int p = s * TILE + t;                      // this thread's point
        const int2 pyx = *(const int2*)(ptsb + p * 2);   // coalesced 8B
        const float u = uvb[pyx.x * WW + pyx.y];
        const float v = uvb[HH * WW + pyx.x * WW + pyx.y];
        const float c = (float)pyx.x * u + (float)pyx.y * v;
        __half* base = (__half*)&tile[t >> 1];
        const int e = t & 1;                             // slot within pack
        base[0 + e] = __float2half_rn(u);
        base[2 + e] = __float2half_rn(v);
        base[4 + e] = __float2half_rn(-c);
    }

    // ---- read precomputed Y, scale (yy, yx, 1) into f16-safe range ----
    const float2 Yn = yv[b * NN + t];
    const float yy = Yn.x, yx = Yn.y;
    const float maxab = fmaxf(fabsf(yy), fabsf(yx));
    const float sc = (maxab > 1024.0f) ? (1024.0f / maxab) : 1.0f;
    const __half2 yy2 = __float2half2_rn(yy * sc);
    const __half2 yx2 = __float2half2_rn(yx * sc);
    const __half2 sc2 = __float2half2_rn(sc);

    __syncthreads();

    // ---- voting: packed f16, 2 points per iteration, sign-bit counting ----
    unsigned negs = 0u;
    #pragma unroll 16
    for (int j = 0; j < TILE2; ++j) {
        const PtPack q = tile[j];                  // broadcast ds_read_b128
        __half2 d = __hmul2(yy2, q.u);
        d = __hfma2(yx2, q.v, d);
        d = __hfma2(sc2, q.nc, d);
        unsigned ub;
        __builtin_memcpy(&ub, &d, 4);
        negs += (ub >> 15) & 0x00010001u;          // sign bits of both halves
    }
    const int cw = TILE - (int)(negs & 0xFFFFu) - (int)(negs >> 16);

    // ---- deterministic reduction of (w*Yy, w*Yx, w) ----
    double wy = (double)cw * (double)yy;
    double wx = (double)cw * (double)yx;
    double ww = (double)cw;
    #pragma unroll
    for (int off = 32; off > 0; off >>= 1) {
        wy += __shfl_down(wy, off);
        wx += __shfl_down(wx, off);
        ww += __shfl_down(ww, off);
    }

    __shared__ double red[4 * 3];
    const int wid = t >> 6;
    if ((t & 63) == 0) {
        red[wid * 3 + 0] = wy;
        red[wid * 3 + 1] = wx;
        red[wid * 3 + 2] = ww;
    }
    __syncthreads();
    if (t == 0) {
        double* o = part + (size_t)blk * 4;
        o[0] = red[0] + red[3] + red[6] + red[9];
        o[1] = red[1] + red[4] + red[7] + red[10];
        o[2] = red[2] + red[5] + red[8] + red[11];
    }
}

// Kernel 3: combine SPLIT=16 partials per batch, divide, write reversed out.
// 256 threads = 32 batches x 8 lanes; each lane sums 2 partials, 3-step
// shfl_xor butterfly within the aligned 8-lane group (deterministic).
__global__ __launch_bounds__(256)
void hough_final(const double* __restrict__ part, float* __restrict__ out)
{
    const int t = threadIdx.x;
    const int bb = t >> 3;
    const int l8 = t & 7;
    double sy = 0.0, sx = 0.0, sw = 0.0;
    #pragma unroll
    for (int k = l8; k < SPLIT; k += 8) {
        const double* o = part + (size_t)(bb * SPLIT + k) * 4;
        sy += o[0];
        sx += o[1];
        sw += o[2];
    }
    #pragma unroll
    for (int off = 1; off < 8; off <<= 1) {
        sy += __shfl_xor(sy, off);
        sx += __shfl_xor(sx, off);
        sw += __shfl_xor(sw, off);
    }
    if (l8 == 0) {
        // weighted_mean = (sy/sw, sx/sw) in (row, col); output is [::-1]
        out[bb * 2 + 0] = (float)(sx / sw);
        out[bb * 2 + 1] = (float)(sy / sw);
    }
}

// ---------------- fallback (solve-in-block, 2-node), used if ws tiny -------
__global__ __launch_bounds__(256, 4)
void hough_partial_fb(const float* __restrict__ uv,
                      const int* __restrict__ pts,
                      const int* __restrict__ pair,
                      double* __restrict__ part)
{
    const int blk = blockIdx.x;
    const int b = blk / SPLIT;
    const int s = blk % SPLIT;
    const int t = threadIdx.x;

    const float* uvb = uv + (size_t)b * CH * HH * WW;
    const int* ptsb = pts + b * PP * 2;

    __shared__ PtPack tile[TILE2];
    {
        const int p = s * TILE + t;
        const int2 pyx = *(const int2*)(ptsb + p * 2);
        const float u = uvb[pyx.x * WW + pyx.y];
        const float v = uvb[HH * WW + pyx.x * WW + pyx.y];
        const float c = (float)pyx.x * u + (float)pyx.y * v;
        __half* base = (__half*)&tile[t >> 1];
        const int e = t & 1;
        base[0 + e] = __float2half_rn(u);
        base[2 + e] = __float2half_rn(v);
        base[4 + e] = __float2half_rn(-c);
    }

    const float2 Yn = solve_pair(uvb, ptsb, pair + b * NN * 2, t);
    const float yy = Yn.x, yx = Yn.y;
    const float maxab = fmaxf(fabsf(yy), fabsf(yx));
    const float sc = (maxab > 1024.0f) ? (1024.0f / maxab) : 1.0f;
    const __half2 yy2 = __float2half2_rn(yy * sc);
    const __half2 yx2 = __float2half2_rn(yx * sc);
    const __half2 sc2 = __float2half2_rn(sc);

    __syncthreads();

    unsigned negs = 0u;
    #pragma unroll 16
    for (int j = 0; j < TILE2; ++j) {
        const PtPack q = tile[j];
        __half2 d = __hmul2(yy2, q.u);
        d = __hfma2(yx2, q.v, d);
        d = __hfma2(sc2, q.nc, d);
        unsigned ub;
        __builtin_memcpy(&ub, &d, 4);
        negs += (ub >> 15) & 0x00010001u;
    }
    const int cw = TILE - (int)(negs & 0xFFFFu) - (int)(negs >> 16);

    double wy = (double)cw * (double)yy;
    double wx = (double)cw * (double)yx;
    double ww = (double)cw;
    #pragma unroll
    for (int off = 32; off > 0; off >>= 1) {
        wy += __shfl_down(wy, off);
        wx += __shfl_down(wx, off);
        ww += __shfl_down(ww, off);
    }
    __shared__ double red[4 * 3];
    const int wid = t >> 6;
    if ((t & 63) == 0) {
        red[wid * 3 + 0] = wy;
        red[wid * 3 + 1] = wx;
        red[wid * 3 + 2] = ww;
    }
    __syncthreads();
    if (t == 0) {
        double* o = part + (size_t)blk * 4;
        o[0] = red[0] + red[3] + red[6] + red[9];
        o[1] = red[1] + red[4] + red[7] + red[10];
        o[2] = red[2] + red[5] + red[8] + red[11];
    }
}

extern "C" void kernel_launch(void* const* d_in, const int* in_sizes, int n_in,
                              void* d_out, int out_size, void* d_ws, size_t ws_size,
                              hipStream_t stream)
{
    const float* uv   = (const float*)d_in[0];   // (B, 2, 224, 224) f32
    const int*   pts  = (const int*)d_in[1];     // (B, 4096, 2) i32
    const int*   pair = (const int*)d_in[2];     // (B, 256, 2) i32
    float* out = (float*)d_out;                  // (B, 2) f32
    char* ws = (char*)d_ws;

    if (ws_size >= WS_NEED) {
        float2* yv   = (float2*)(ws + WS_Y_OFF);
        double* part = (double*)(ws + WS_PART_OFF);
        hough_solve<<<128, 64, 0, stream>>>(uv, pts, pair, yv);
        hough_vote<<<BATCH * SPLIT, 256, 0, stream>>>(uv, pts, yv, part);
        hough_final<<<1, 256, 0, stream>>>(part, out);
    } else {
        double* part = (double*)ws;              // 16 KB
        hough_partial_fb<<<BATCH * SPLIT, 256, 0, stream>>>(uv, pts, pair, part);
        hough_final<<<1, 256, 0, stream>>>(part, out);
    }
}

// Round 9
// 19.440 us; speedup vs baseline: 1.1530x; 1.0240x over previous
//
#include <hip/hip_runtime.h>
#include <hip/hip_fp16.h>

// Problem constants (match reference)
#define BATCH 32
#define CH    2
#define HH    224
#define WW    224
#define PP    4096
#define NN    256
#define SPLIT 16
#define NBLK  (BATCH * SPLIT)   // 512 vote blocks
#define TILE  (PP / SPLIT)      // 256 points per block
#define TILE2 (TILE / 2)        // 128 packed point-pairs

// ws layout: [0,64K) float2 Y[B*N]; then SoA float partials sy/sx/sw[512].
#define WS_Y_OFF    0
#define WS_SY_OFF   (64 * 1024)
#define WS_SX_OFF   (WS_SY_OFF + NBLK * 4)
#define WS_SW_OFF   (WS_SX_OFF + NBLK * 4)
#define WS_NEED     (WS_SW_OFF + NBLK * 4)

// Packed vote-point pair: (u0,u1),(v0,v1),(-c0,-c1) in f16, padded to 16B so
// the vote loop reads one ds_read_b128 (broadcast) per TWO points.
// c = py*u + px*v, so agree = sign(yy*u + yx*v - c)  (the reference's
// normalization can't flip the sign, so the norm is dropped).
struct alignas(16) PtPack { __half2 u, v, nc, pad; };

// ---- shared solve: 2x2 pinv (f64, matches jnp.linalg.pinv semantics) ----
__device__ inline float2 solve_pair(const float* __restrict__ uvb,
                                    const int* __restrict__ ptsb,
                                    const int* __restrict__ pairb, int n)
{
    const int2 pr = *(const int2*)(pairb + n * 2);
    const int2 p0 = *(const int2*)(ptsb + pr.x * 2);
    const int2 p1 = *(const int2*)(ptsb + pr.y * 2);
    const int y0 = p0.x, x0 = p0.y;
    const int y1 = p1.x, x1 = p1.y;

    const float u0a = uvb[y0 * WW + x0];                 // uv[0] at pt0
    const float u0b = uvb[HH * WW + y0 * WW + x0];       // uv[1] at pt0
    const float u1a = uvb[y1 * WW + x1];                 // uv[0] at pt1
    const float u1b = uvb[HH * WW + y1 * WW + x1];       // uv[1] at pt1

    const double a00 = (double)u0a, a01 = -(double)u1a;
    const double a10 = (double)u0b, a11 = -(double)u1b;
    const double b0 = (double)(y1 - y0), b1 = (double)(x1 - x0);
    const double det = a00 * a11 - a01 * a10;
    const double frob2 = a00 * a00 + a01 * a01 + a10 * a10 + a11 * a11;

    double t0;
    if (fabs(det) > 1e-12 * frob2) {
        t0 = (b0 * a11 - b1 * a01) / det;          // first row of A^{-1} b
    } else if (frob2 > 0.0) {
        t0 = (a00 * b0 + a10 * b1) / frob2;        // rank-1 pinv: A^T b / ||A||_F^2
    } else {
        t0 = 0.0;
    }
    return make_float2((float)(t0 * (double)u0a + (double)y0),   // row
                       (float)(t0 * (double)u0b + (double)x0));  // col
}

// Kernel 1: solve every (b,n) ONCE, 128 blocks x 64 threads (one item per
// thread, fully parallel 3-deep gather chain). No atomics, no fences.
__global__ __launch_bounds__(64)
void hough_solve(const float* __restrict__ uv,
                 const int* __restrict__ pts,
                 const int* __restrict__ pair,
                 float2* __restrict__ yv)
{
    const int blk = blockIdx.x;          // 128 blocks: 4 per batch
    const int b = blk >> 2;
    const int n = ((blk & 3) << 6) + threadIdx.x;
    const float* uvb = uv + (size_t)b * CH * HH * WW;
    yv[b * NN + n] = solve_pair(uvb, pts + b * PP * 2, pair + b * NN * 2, n);
}

// Kernel 2: one block per (batch, point-tile). 256 threads, one per pair n.
//   1. stage TILE=256 points: EVERY thread stages one point (2 scattered
//      gathers + 3 ds_write_b16; 2-way bank alias free)
//   2. read Y (coalesced 8B), rescale into f16-safe range
//   3. packed-f16 vote over 128 packs, sign-bit counting
//   4. float wave-shuffle reduce -> SoA float partials (coalesced 4B writes)
__global__ __launch_bounds__(256, 4)
void hough_vote(const float* __restrict__ uv,
                const int* __restrict__ pts,
                const float2* __restrict__ yv,
                float* __restrict__ psy,
                float* __restrict__ psx,
                float* __restrict__ psw)
{
    const int blk = blockIdx.x;
    const int b = blk / SPLIT;
    const int s = blk % SPLIT;
    const int t = threadIdx.x;   // n = t

    const float* uvb = uv + (size_t)b * CH * HH * WW;
    const int* ptsb = pts + b * PP * 2;

    // ---- stage: one point per thread into the f16 pack layout ----
    __shared__ PtPack tile[TILE2];
    {
        const int p = s * TILE + t;                      // this thread's point
        const int2 pyx = *(const int2*)(ptsb + p * 2);   // coalesced 8B
        const float u = uvb[pyx.x * WW + pyx.y];
        const float v = uvb[HH * WW + pyx.x * WW + pyx.y];
        const float c = (float)pyx.x * u + (float)pyx.y * v;
        __half* base = (__half*)&tile[t >> 1];
        const int e = t & 1;                             // slot within pack
        base[0 + e] = __float2half_rn(u);
        base[2 + e] = __float2half_rn(v);
        base[4 + e] = __float2half_rn(-c);
    }

    // ---- read precomputed Y, scale (yy, yx, 1) into f16-safe range ----
    const float2 Yn = yv[b * NN + t];
    const float yy = Yn.x, yx = Yn.y;
    const float maxab = fmaxf(fabsf(yy), fabsf(yx));
    const float sc = (maxab > 1024.0f) ? (1024.0f / maxab) : 1.0f;
    const __half2 yy2 = __float2half2_rn(yy * sc);
    const __half2 yx2 = __float2half2_rn(yx * sc);
    const __half2 sc2 = __float2half2_rn(sc);

    __syncthreads();

    // ---- voting: packed f16, 2 points per iteration, sign-bit counting ----
    unsigned negs = 0u;
    #pragma unroll 16
    for (int j = 0; j < TILE2; ++j) {
        const PtPack q = tile[j];                  // broadcast ds_read_b128
        __half2 d = __hmul2(yy2, q.u);
        d = __hfma2(yx2, q.v, d);
        d = __hfma2(sc2, q.nc, d);
        unsigned ub;
        __builtin_memcpy(&ub, &d, 4);
        negs += (ub >> 15) & 0x00010001u;          // sign bits of both halves
    }
    const int cw = TILE - (int)(negs & 0xFFFFu) - (int)(negs >> 16);

    // ---- reduction of (w*Yy, w*Yx, w): float shuffles, fixed order ----
    float wy = (float)cw * yy;
    float wx = (float)cw * yx;
    float ww = (float)cw;
    #pragma unroll
    for (int off = 32; off > 0; off >>= 1) {
        wy += __shfl_down(wy, off);
        wx += __shfl_down(wx, off);
        ww += __shfl_down(ww, off);
    }

    __shared__ float red[4 * 3];
    const int wid = t >> 6;
    if ((t & 63) == 0) {
        red[wid * 3 + 0] = wy;
        red[wid * 3 + 1] = wx;
        red[wid * 3 + 2] = ww;
    }
    __syncthreads();
    if (t == 0) {
        psy[blk] = red[0] + red[3] + red[6] + red[9];
        psx[blk] = red[1] + red[4] + red[7] + red[10];
        psw[blk] = red[2] + red[5] + red[8] + red[11];
    }
}

// Kernel 3: combine SPLIT=16 float partials per batch in double (fixed
// order), divide, write reversed output. 256 threads = 32 batches x 8
// lanes; lane reads one float2 from each SoA array (fully coalesced).
__global__ __launch_bounds__(256)
void hough_final(const float* __restrict__ psy,
                 const float* __restrict__ psx,
                 const float* __restrict__ psw,
                 float* __restrict__ out)
{
    const int t = threadIdx.x;
    const int bb = t >> 3;
    const int l8 = t & 7;
    const int k = bb * SPLIT + l8 * 2;          // == t*2: coalesced float2

    const float2 vy = *(const float2*)(psy + k);
    const float2 vx = *(const float2*)(psx + k);
    const float2 vw = *(const float2*)(psw + k);
    double sy = (double)vy.x + (double)vy.y;
    double sx = (double)vx.x + (double)vx.y;
    double sw = (double)vw.x + (double)vw.y;
    #pragma unroll
    for (int off = 1; off < 8; off <<= 1) {
        sy += __shfl_xor(sy, off);
        sx += __shfl_xor(sx, off);
        sw += __shfl_xor(sw, off);
    }
    if (l8 == 0) {
        // weighted_mean = (sy/sw, sx/sw) in (row, col); output is [::-1]
        out[bb * 2 + 0] = (float)(sx / sw);
        out[bb * 2 + 1] = (float)(sy / sw);
    }
}

// ---------------- fallback (solve-in-block, 2-node), used if ws tiny -------
__global__ __launch_bounds__(256, 4)
void hough_partial_fb(const float* __restrict__ uv,
                      const int* __restrict__ pts,
                      const int* __restrict__ pair,
                      float* __restrict__ psy,
                      float* __restrict__ psx,
                      float* __restrict__ psw)
{
    const int blk = blockIdx.x;
    const int b = blk / SPLIT;
    const int s = blk % SPLIT;
    const int t = threadIdx.x;

    const float* uvb = uv + (size_t)b * CH * HH * WW;
    const int* ptsb = pts + b * PP * 2;

    __shared__ PtPack tile[TILE2];
    {
        const int p = s * TILE + t;
        const int2 pyx = *(const int2*)(ptsb + p * 2);
        const float u = uvb[pyx.x * WW + pyx.y];
        const float v = uvb[HH * WW + pyx.x * WW + pyx.y];
        const float c = (float)pyx.x * u + (float)pyx.y * v;
        __half* base = (__half*)&tile[t >> 1];
        const int e = t & 1;
        base[0 + e] = __float2half_rn(u);
        base[2 + e] = __float2half_rn(v);
        base[4 + e] = __float2half_rn(-c);
    }

    const float2 Yn = solve_pair(uvb, ptsb, pair + b * NN * 2, t);
    const float yy = Yn.x, yx = Yn.y;
    const float maxab = fmaxf(fabsf(yy), fabsf(yx));
    const float sc = (maxab > 1024.0f) ? (1024.0f / maxab) : 1.0f;
    const __half2 yy2 = __float2half2_rn(yy * sc);
    const __half2 yx2 = __float2half2_rn(yx * sc);
    const __half2 sc2 = __float2half2_rn(sc);

    __syncthreads();

    unsigned negs = 0u;
    #pragma unroll 16
    for (int j = 0; j < TILE2; ++j) {
        const PtPack q = tile[j];
        __half2 d = __hmul2(yy2, q.u);
        d = __hfma2(yx2, q.v, d);
        d = __hfma2(sc2, q.nc, d);
        unsigned ub;
        __builtin_memcpy(&ub, &d, 4);
        negs += (ub >> 15) & 0x00010001u;
    }
    const int cw = TILE - (int)(negs & 0xFFFFu) - (int)(negs >> 16);

    float wy = (float)cw * yy;
    float wx = (float)cw * yx;
    float ww = (float)cw;
    #pragma unroll
    for (int off = 32; off > 0; off >>= 1) {
        wy += __shfl_down(wy, off);
        wx += __shfl_down(wx, off);
        ww += __shfl_down(ww, off);
    }
    __shared__ float red[4 * 3];
    const int wid = t >> 6;
    if ((t & 63) == 0) {
        red[wid * 3 + 0] = wy;
        red[wid * 3 + 1] = wx;
        red[wid * 3 + 2] = ww;
    }
    __syncthreads();
    if (t == 0) {
        psy[blk] = red[0] + red[3] + red[6] + red[9];
        psx[blk] = red[1] + red[4] + red[7] + red[10];
        psw[blk] = red[2] + red[5] + red[8] + red[11];
    }
}

extern "C" void kernel_launch(void* const* d_in, const int* in_sizes, int n_in,
                              void* d_out, int out_size, void* d_ws, size_t ws_size,
                              hipStream_t stream)
{
    const float* uv   = (const float*)d_in[0];   // (B, 2, 224, 224) f32
    const int*   pts  = (const int*)d_in[1];     // (B, 4096, 2) i32
    const int*   pair = (const int*)d_in[2];     // (B, 256, 2) i32
    float* out = (float*)d_out;                  // (B, 2) f32
    char* ws = (char*)d_ws;

    float* psy = (float*)(ws + WS_SY_OFF);
    float* psx = (float*)(ws + WS_SX_OFF);
    float* psw = (float*)(ws + WS_SW_OFF);

    if (ws_size >= WS_NEED) {
        float2* yv = (float2*)(ws + WS_Y_OFF);
        hough_solve<<<128, 64, 0, stream>>>(uv, pts, pair, yv);
        hough_vote<<<NBLK, 256, 0, stream>>>(uv, pts, yv, psy, psx, psw);
        hough_final<<<1, 256, 0, stream>>>(psy, psx, psw, out);
    } else {
        // 2-node fallback: partials at ws base (6 KB)
        psy = (float*)ws; psx = psy + NBLK; psw = psx + NBLK;
        hough_partial_fb<<<NBLK, 256, 0, stream>>>(uv, pts, pair, psy, psx, psw);
        hough_final<<<1, 256, 0, stream>>>(psy, psx, psw, out);
    }
}

// Round 10
// 18.328 us; speedup vs baseline: 1.2229x; 1.0606x over previous
//
#include <hip/hip_runtime.h>
#include <hip/hip_fp16.h>

// Problem constants (match reference)
#define BATCH 32
#define CH    2
#define HH    224
#define WW    224
#define PP    4096
#define NN    256
#define SPLIT 16
#define NBLK  (BATCH * SPLIT)   // 512 vote blocks
#define TILE  (PP / SPLIT)      // 256 points per block
#define TILE2 (TILE / 2)        // 128 packed point-pairs
#define WPACKS (TILE2 / 4)      // 32 packs per wave (disjoint quarter)

// ws layout: [0,64K) float2 Y[B*N]; then SoA float partials sy/sx/sw[512].
#define WS_Y_OFF    0
#define WS_SY_OFF   (64 * 1024)
#define WS_SX_OFF   (WS_SY_OFF + NBLK * 4)
#define WS_SW_OFF   (WS_SX_OFF + NBLK * 4)
#define WS_NEED     (WS_SW_OFF + NBLK * 4)

// Packed vote-point pair: (u0,u1),(v0,v1),(-c0,-c1) in f16, padded to 16B so
// one ds_read_b128 (broadcast) covers TWO points. c = py*u + px*v, so
// agree = sign(yy*u + yx*v - c) (normalization can't flip the sign).
struct alignas(16) PtPack { __half2 u, v, nc, pad; };

// ---- shared solve: 2x2 pinv (f64, matches jnp.linalg.pinv semantics) ----
__device__ inline float2 solve_pair(const float* __restrict__ uvb,
                                    const int* __restrict__ ptsb,
                                    const int* __restrict__ pairb, int n)
{
    const int2 pr = *(const int2*)(pairb + n * 2);
    const int2 p0 = *(const int2*)(ptsb + pr.x * 2);
    const int2 p1 = *(const int2*)(ptsb + pr.y * 2);
    const int y0 = p0.x, x0 = p0.y;
    const int y1 = p1.x, x1 = p1.y;

    const float u0a = uvb[y0 * WW + x0];                 // uv[0] at pt0
    const float u0b = uvb[HH * WW + y0 * WW + x0];       // uv[1] at pt0
    const float u1a = uvb[y1 * WW + x1];                 // uv[0] at pt1
    const float u1b = uvb[HH * WW + y1 * WW + x1];       // uv[1] at pt1

    const double a00 = (double)u0a, a01 = -(double)u1a;
    const double a10 = (double)u0b, a11 = -(double)u1b;
    const double b0 = (double)(y1 - y0), b1 = (double)(x1 - x0);
    const double det = a00 * a11 - a01 * a10;
    const double frob2 = a00 * a00 + a01 * a01 + a10 * a10 + a11 * a11;

    double t0;
    if (fabs(det) > 1e-12 * frob2) {
        t0 = (b0 * a11 - b1 * a01) / det;          // first row of A^{-1} b
    } else if (frob2 > 0.0) {
        t0 = (a00 * b0 + a10 * b1) / frob2;        // rank-1 pinv: A^T b / ||A||_F^2
    } else {
        t0 = 0.0;
    }
    return make_float2((float)(t0 * (double)u0a + (double)y0),   // row
                       (float)(t0 * (double)u0b + (double)x0));  // col
}

// Kernel 1: solve every (b,n) ONCE, 128 blocks x 64 threads.
__global__ __launch_bounds__(64)
void hough_solve(const float* __restrict__ uv,
                 const int* __restrict__ pts,
                 const int* __restrict__ pair,
                 float2* __restrict__ yv)
{
    const int blk = blockIdx.x;          // 128 blocks: 4 per batch
    const int b = blk >> 2;
    const int n = ((blk & 3) << 6) + threadIdx.x;
    const float* uvb = uv + (size_t)b * CH * HH * WW;
    yv[b * NN + n] = solve_pair(uvb, pts + b * PP * 2, pair + b * NN * 2, n);
}

// Kernel 2: one block per (batch, point-tile). 256 threads.
// Each LANE owns 4 n-values (n = lane + 64g); each WAVE processes a disjoint
// quarter of the tile (WPACKS packs). One ds_read_b128 now feeds 4 n-groups
// (24 VALU, 512 dots) -> LDS-pipe traffic per CU drops 4x vs one-n-per-thread.
__global__ __launch_bounds__(256, 4)
void hough_vote(const float* __restrict__ uv,
                const int* __restrict__ pts,
                const float2* __restrict__ yv,
                float* __restrict__ psy,
                float* __restrict__ psx,
                float* __restrict__ psw)
{
    const int blk = blockIdx.x;
    const int b = blk / SPLIT;
    const int s = blk % SPLIT;
    const int t = threadIdx.x;
    const int wave = t >> 6;
    const int lane = t & 63;

    const float* uvb = uv + (size_t)b * CH * HH * WW;
    const int* ptsb = pts + b * PP * 2;

    // ---- stage: one point per thread into the f16 pack layout ----
    __shared__ PtPack tile[TILE2];
    {
        const int p = s * TILE + t;                      // this thread's point
        const int2 pyx = *(const int2*)(ptsb + p * 2);   // coalesced 8B
        const float u = uvb[pyx.x * WW + pyx.y];
        const float v = uvb[HH * WW + pyx.x * WW + pyx.y];
        const float c = (float)pyx.x * u + (float)pyx.y * v;
        __half* base = (__half*)&tile[t >> 1];
        const int e = t & 1;                             // slot within pack
        base[0 + e] = __float2half_rn(u);
        base[2 + e] = __float2half_rn(v);
        base[4 + e] = __float2half_rn(-c);
    }

    // ---- per-lane: load 4 Y values (n = lane + 64g), build f16 operands ----
    float yyf[4], yxf[4];
    __half2 yy2[4], yx2[4], sc2[4];
    #pragma unroll
    for (int g = 0; g < 4; ++g) {
        const float2 Yn = yv[b * NN + lane + 64 * g];
        yyf[g] = Yn.x;
        yxf[g] = Yn.y;
        const float maxab = fmaxf(fabsf(Yn.x), fabsf(Yn.y));
        const float sc = (maxab > 1024.0f) ? (1024.0f / maxab) : 1.0f;
        yy2[g] = __float2half2_rn(Yn.x * sc);
        yx2[g] = __float2half2_rn(Yn.y * sc);
        sc2[g] = __float2half2_rn(sc);
    }

    __syncthreads();

    // ---- voting: this wave's disjoint WPACKS packs x 4 n-groups ----
    unsigned negs0 = 0u, negs1 = 0u, negs2 = 0u, negs3 = 0u;
    const PtPack* wp = tile + wave * WPACKS;
    #pragma unroll 8
    for (int j = 0; j < WPACKS; ++j) {
        const PtPack q = wp[j];                    // broadcast ds_read_b128
        unsigned ub;
        __half2 d;
        d = __hmul2(yy2[0], q.u); d = __hfma2(yx2[0], q.v, d); d = __hfma2(sc2[0], q.nc, d);
        __builtin_memcpy(&ub, &d, 4); negs0 += (ub >> 15) & 0x00010001u;
        d = __hmul2(yy2[1], q.u); d = __hfma2(yx2[1], q.v, d); d = __hfma2(sc2[1], q.nc, d);
        __builtin_memcpy(&ub, &d, 4); negs1 += (ub >> 15) & 0x00010001u;
        d = __hmul2(yy2[2], q.u); d = __hfma2(yx2[2], q.v, d); d = __hfma2(sc2[2], q.nc, d);
        __builtin_memcpy(&ub, &d, 4); negs2 += (ub >> 15) & 0x00010001u;
        d = __hmul2(yy2[3], q.u); d = __hfma2(yx2[3], q.v, d); d = __hfma2(sc2[3], q.nc, d);
        __builtin_memcpy(&ub, &d, 4); negs3 += (ub >> 15) & 0x00010001u;
    }

    // ---- per-lane weighted partials over this wave's points ----
    const int pts_per_lane = 2 * WPACKS;           // 64 points
    const int c0 = pts_per_lane - (int)(negs0 & 0xFFFFu) - (int)(negs0 >> 16);
    const int c1 = pts_per_lane - (int)(negs1 & 0xFFFFu) - (int)(negs1 >> 16);
    const int c2 = pts_per_lane - (int)(negs2 & 0xFFFFu) - (int)(negs2 >> 16);
    const int c3 = pts_per_lane - (int)(negs3 & 0xFFFFu) - (int)(negs3 >> 16);

    float wy = (float)c0 * yyf[0] + (float)c1 * yyf[1]
             + (float)c2 * yyf[2] + (float)c3 * yyf[3];
    float wx = (float)c0 * yxf[0] + (float)c1 * yxf[1]
             + (float)c2 * yxf[2] + (float)c3 * yxf[3];
    float ww = (float)(c0 + c1 + c2 + c3);

    #pragma unroll
    for (int off = 32; off > 0; off >>= 1) {
        wy += __shfl_down(wy, off);
        wx += __shfl_down(wx, off);
        ww += __shfl_down(ww, off);
    }

    __shared__ float red[4 * 3];
    if (lane == 0) {
        red[wave * 3 + 0] = wy;
        red[wave * 3 + 1] = wx;
        red[wave * 3 + 2] = ww;
    }
    __syncthreads();
    if (t == 0) {
        psy[blk] = red[0] + red[3] + red[6] + red[9];
        psx[blk] = red[1] + red[4] + red[7] + red[10];
        psw[blk] = red[2] + red[5] + red[8] + red[11];
    }
}

// Kernel 3: combine SPLIT=16 float partials per batch in double (fixed
// order), divide, write reversed output. Coalesced float2 reads.
__global__ __launch_bounds__(256)
void hough_final(const float* __restrict__ psy,
                 const float* __restrict__ psx,
                 const float* __restrict__ psw,
                 float* __restrict__ out)
{
    const int t = threadIdx.x;
    const int bb = t >> 3;
    const int l8 = t & 7;
    const int k = bb * SPLIT + l8 * 2;          // == t*2: coalesced float2

    const float2 vy = *(const float2*)(psy + k);
    const float2 vx = *(const float2*)(psx + k);
    const float2 vw = *(const float2*)(psw + k);
    double sy = (double)vy.x + (double)vy.y;
    double sx = (double)vx.x + (double)vx.y;
    double sw = (double)vw.x + (double)vw.y;
    #pragma unroll
    for (int off = 1; off < 8; off <<= 1) {
        sy += __shfl_xor(sy, off);
        sx += __shfl_xor(sx, off);
        sw += __shfl_xor(sw, off);
    }
    if (l8 == 0) {
        // weighted_mean = (sy/sw, sx/sw) in (row, col); output is [::-1]
        out[bb * 2 + 0] = (float)(sx / sw);
        out[bb * 2 + 1] = (float)(sy / sw);
    }
}

// ---------------- fallback (solve-in-block, 2-node), used if ws tiny -------
__global__ __launch_bounds__(256, 4)
void hough_partial_fb(const float* __restrict__ uv,
                      const int* __restrict__ pts,
                      const int* __restrict__ pair,
                      float* __restrict__ psy,
                      float* __restrict__ psx,
                      float* __restrict__ psw)
{
    const int blk = blockIdx.x;
    const int b = blk / SPLIT;
    const int s = blk % SPLIT;
    const int t = threadIdx.x;

    const float* uvb = uv + (size_t)b * CH * HH * WW;
    const int* ptsb = pts + b * PP * 2;

    __shared__ PtPack tile[TILE2];
    {
        const int p = s * TILE + t;
        const int2 pyx = *(const int2*)(ptsb + p * 2);
        const float u = uvb[pyx.x * WW + pyx.y];
        const float v = uvb[HH * WW + pyx.x * WW + pyx.y];
        const float c = (float)pyx.x * u + (float)pyx.y * v;
        __half* base = (__half*)&tile[t >> 1];
        const int e = t & 1;
        base[0 + e] = __float2half_rn(u);
        base[2 + e] = __float2half_rn(v);
        base[4 + e] = __float2half_rn(-c);
    }

    const float2 Yn = solve_pair(uvb, ptsb, pair + b * NN * 2, t);
    const float yy = Yn.x, yx = Yn.y;
    const float maxab = fmaxf(fabsf(yy), fabsf(yx));
    const float sc = (maxab > 1024.0f) ? (1024.0f / maxab) : 1.0f;
    const __half2 yy2 = __float2half2_rn(yy * sc);
    const __half2 yx2 = __float2half2_rn(yx * sc);
    const __half2 sc2 = __float2half2_rn(sc);

    __syncthreads();

    unsigned negs = 0u;
    #pragma unroll 16
    for (int j = 0; j < TILE2; ++j) {
        const PtPack q = tile[j];
        __half2 d = __hmul2(yy2, q.u);
        d = __hfma2(yx2, q.v, d);
        d = __hfma2(sc2, q.nc, d);
        unsigned ub;
        __builtin_memcpy(&ub, &d, 4);
        negs += (ub >> 15) & 0x00010001u;
    }
    const int cw = TILE - (int)(negs & 0xFFFFu) - (int)(negs >> 16);

    float wy = (float)cw * yy;
    float wx = (float)cw * yx;
    float ww = (float)cw;
    #pragma unroll
    for (int off = 32; off > 0; off >>= 1) {
        wy += __shfl_down(wy, off);
        wx += __shfl_down(wx, off);
        ww += __shfl_down(ww, off);
    }
    __shared__ float red[4 * 3];
    const int wid = t >> 6;
    if ((t & 63) == 0) {
        red[wid * 3 + 0] = wy;
        red[wid * 3 + 1] = wx;
        red[wid * 3 + 2] = ww;
    }
    __syncthreads();
    if (t == 0) {
        psy[blk] = red[0] + red[3] + red[6] + red[9];
        psx[blk] = red[1] + red[4] + red[7] + red[10];
        psw[blk] = red[2] + red[5] + red[8] + red[11];
    }
}

extern "C" void kernel_launch(void* const* d_in, const int* in_sizes, int n_in,
                              void* d_out, int out_size, void* d_ws, size_t ws_size,
                              hipStream_t stream)
{
    const float* uv   = (const float*)d_in[0];   // (B, 2, 224, 224) f32
    const int*   pts  = (const int*)d_in[1];     // (B, 4096, 2) i32
    const int*   pair = (const int*)d_in[2];     // (B, 256, 2) i32
    float* out = (float*)d_out;                  // (B, 2) f32
    char* ws = (char*)d_ws;

    float* psy = (float*)(ws + WS_SY_OFF);
    float* psx = (float*)(ws + WS_SX_OFF);
    float* psw = (float*)(ws + WS_SW_OFF);

    if (ws_size >= WS_NEED) {
        float2* yv = (float2*)(ws + WS_Y_OFF);
        hough_solve<<<128, 64, 0, stream>>>(uv, pts, pair, yv);
        hough_vote<<<NBLK, 256, 0, stream>>>(uv, pts, yv, psy, psx, psw);
        hough_final<<<1, 256, 0, stream>>>(psy, psx, psw, out);
    } else {
        // 2-node fallback: partials at ws base (6 KB)
        psy = (float*)ws; psx = psy + NBLK; psw = psx + NBLK;
        hough_partial_fb<<<NBLK, 256, 0, stream>>>(uv, pts, pair, psy, psx, psw);
        hough_final<<<1, 256, 0, stream>>>(psy, psx, psw, out);
    }
}

// Round 11
// 18.266 us; speedup vs baseline: 1.2270x; 1.0034x over previous
//
#include <hip/hip_runtime.h>
#include <hip/hip_fp16.h>

// Problem constants (match reference)
#define BATCH 32
#define CH    2
#define HH    224
#define WW    224
#define PP    4096
#define NN    256
#define SPLIT 16
#define NBLK  (BATCH * SPLIT)   // 512 vote blocks
#define TILE  (PP / SPLIT)      // 256 points per block
#define TILE2 (TILE / 2)        // 128 packed point-pairs
#define WPACKS (TILE2 / 4)      // 32 packs per wave (disjoint quarter)

// ws layout: SoA float partials sy/sx/sw[512] (6 KB).
#define WS_SY_OFF   0
#define WS_SX_OFF   (NBLK * 4)
#define WS_SW_OFF   (NBLK * 8)

// Packed vote-point pair: (u0,u1),(v0,v1),(-c0,-c1) in f16, padded to 16B so
// one ds_read_b128 (broadcast) covers TWO points. c = py*u + px*v, so
// agree = sign(yy*u + yx*v - c) (normalization can't flip the sign).
struct alignas(16) PtPack { __half2 u, v, nc, pad; };

// ---- shared solve: 2x2 pinv (f64, matches jnp.linalg.pinv semantics) ----
__device__ inline float2 solve_pair(const float* __restrict__ uvb,
                                    const int* __restrict__ ptsb,
                                    const int* __restrict__ pairb, int n)
{
    const int2 pr = *(const int2*)(pairb + n * 2);
    const int2 p0 = *(const int2*)(ptsb + pr.x * 2);
    const int2 p1 = *(const int2*)(ptsb + pr.y * 2);
    const int y0 = p0.x, x0 = p0.y;
    const int y1 = p1.x, x1 = p1.y;

    const float u0a = uvb[y0 * WW + x0];                 // uv[0] at pt0
    const float u0b = uvb[HH * WW + y0 * WW + x0];       // uv[1] at pt0
    const float u1a = uvb[y1 * WW + x1];                 // uv[0] at pt1
    const float u1b = uvb[HH * WW + y1 * WW + x1];       // uv[1] at pt1

    const double a00 = (double)u0a, a01 = -(double)u1a;
    const double a10 = (double)u0b, a11 = -(double)u1b;
    const double b0 = (double)(y1 - y0), b1 = (double)(x1 - x0);
    const double det = a00 * a11 - a01 * a10;
    const double frob2 = a00 * a00 + a01 * a01 + a10 * a10 + a11 * a11;

    double t0;
    if (fabs(det) > 1e-12 * frob2) {
        t0 = (b0 * a11 - b1 * a01) / det;          // first row of A^{-1} b
    } else if (frob2 > 0.0) {
        t0 = (a00 * b0 + a10 * b1) / frob2;        // rank-1 pinv: A^T b / ||A||_F^2
    } else {
        t0 = 0.0;
    }
    return make_float2((float)(t0 * (double)u0a + (double)y0),   // row
                       (float)(t0 * (double)u0b + (double)x0));  // col
}

// Fused kernel: one block per (batch, point-tile). 256 threads.
//   1. stage TILE=256 points (one per thread: 2 scattered gathers + 3
//      ds_write_b16) AND solve n=t (6 scattered gathers + f64 pinv) into a
//      2 KB LDS float2[256]. All loads issued before one __syncthreads.
//   2. each lane reads its 4 Y from LDS (stride-8B: 2-way alias, free)
//   3. amortized vote: wave-disjoint quarter, 1 ds_read_b128 -> 4 n-groups
//   4. float wave-shuffle reduce -> SoA float partials (coalesced writes)
__global__ __launch_bounds__(256, 4)
void hough_fused(const float* __restrict__ uv,
                 const int* __restrict__ pts,
                 const int* __restrict__ pair,
                 float* __restrict__ psy,
                 float* __restrict__ psx,
                 float* __restrict__ psw)
{
    const int blk = blockIdx.x;
    const int b = blk / SPLIT;
    const int s = blk % SPLIT;
    const int t = threadIdx.x;
    const int wave = t >> 6;
    const int lane = t & 63;

    const float* uvb = uv + (size_t)b * CH * HH * WW;
    const int* ptsb = pts + b * PP * 2;

    __shared__ PtPack tile[TILE2];
    __shared__ float2 yv_lds[NN];

    // ---- stage: one point per thread into the f16 pack layout ----
    {
        const int p = s * TILE + t;                      // this thread's point
        const int2 pyx = *(const int2*)(ptsb + p * 2);   // coalesced 8B
        const float u = uvb[pyx.x * WW + pyx.y];
        const float v = uvb[HH * WW + pyx.x * WW + pyx.y];
        const float c = (float)pyx.x * u + (float)pyx.y * v;
        __half* base = (__half*)&tile[t >> 1];
        const int e = t & 1;                             // slot within pack
        base[0 + e] = __float2half_rn(u);
        base[2 + e] = __float2half_rn(v);
        base[4 + e] = __float2half_rn(-c);
    }

    // ---- solve n=t for this batch (once per block; 6 L2-hit gathers) ----
    yv_lds[t] = solve_pair(uvb, ptsb, pair + b * NN * 2, t);

    __syncthreads();

    // ---- per-lane: read 4 Y values (n = lane + 64g), build f16 operands ----
    float yyf[4], yxf[4];
    __half2 yy2[4], yx2[4], sc2[4];
    #pragma unroll
    for (int g = 0; g < 4; ++g) {
        const float2 Yn = yv_lds[lane + 64 * g];
        yyf[g] = Yn.x;
        yxf[g] = Yn.y;
        const float maxab = fmaxf(fabsf(Yn.x), fabsf(Yn.y));
        const float sc = (maxab > 1024.0f) ? (1024.0f / maxab) : 1.0f;
        yy2[g] = __float2half2_rn(Yn.x * sc);
        yx2[g] = __float2half2_rn(Yn.y * sc);
        sc2[g] = __float2half2_rn(sc);
    }

    // ---- voting: this wave's disjoint WPACKS packs x 4 n-groups ----
    unsigned negs0 = 0u, negs1 = 0u, negs2 = 0u, negs3 = 0u;
    const PtPack* wp = tile + wave * WPACKS;
    #pragma unroll 8
    for (int j = 0; j < WPACKS; ++j) {
        const PtPack q = wp[j];                    // broadcast ds_read_b128
        unsigned ub;
        __half2 d;
        d = __hmul2(yy2[0], q.u); d = __hfma2(yx2[0], q.v, d); d = __hfma2(sc2[0], q.nc, d);
        __builtin_memcpy(&ub, &d, 4); negs0 += (ub >> 15) & 0x00010001u;
        d = __hmul2(yy2[1], q.u); d = __hfma2(yx2[1], q.v, d); d = __hfma2(sc2[1], q.nc, d);
        __builtin_memcpy(&ub, &d, 4); negs1 += (ub >> 15) & 0x00010001u;
        d = __hmul2(yy2[2], q.u); d = __hfma2(yx2[2], q.v, d); d = __hfma2(sc2[2], q.nc, d);
        __builtin_memcpy(&ub, &d, 4); negs2 += (ub >> 15) & 0x00010001u;
        d = __hmul2(yy2[3], q.u); d = __hfma2(yx2[3], q.v, d); d = __hfma2(sc2[3], q.nc, d);
        __builtin_memcpy(&ub, &d, 4); negs3 += (ub >> 15) & 0x00010001u;
    }

    // ---- per-lane weighted partials over this wave's points ----
    const int pts_per_lane = 2 * WPACKS;           // 64 points
    const int c0 = pts_per_lane - (int)(negs0 & 0xFFFFu) - (int)(negs0 >> 16);
    const int c1 = pts_per_lane - (int)(negs1 & 0xFFFFu) - (int)(negs1 >> 16);
    const int c2 = pts_per_lane - (int)(negs2 & 0xFFFFu) - (int)(negs2 >> 16);
    const int c3 = pts_per_lane - (int)(negs3 & 0xFFFFu) - (int)(negs3 >> 16);

    float wy = (float)c0 * yyf[0] + (float)c1 * yyf[1]
             + (float)c2 * yyf[2] + (float)c3 * yyf[3];
    float wx = (float)c0 * yxf[0] + (float)c1 * yxf[1]
             + (float)c2 * yxf[2] + (float)c3 * yxf[3];
    float ww = (float)(c0 + c1 + c2 + c3);

    #pragma unroll
    for (int off = 32; off > 0; off >>= 1) {
        wy += __shfl_down(wy, off);
        wx += __shfl_down(wx, off);
        ww += __shfl_down(ww, off);
    }

    __shared__ float red[4 * 3];
    if (lane == 0) {
        red[wave * 3 + 0] = wy;
        red[wave * 3 + 1] = wx;
        red[wave * 3 + 2] = ww;
    }
    __syncthreads();
    if (t == 0) {
        psy[blk] = red[0] + red[3] + red[6] + red[9];
        psx[blk] = red[1] + red[4] + red[7] + red[10];
        psw[blk] = red[2] + red[5] + red[8] + red[11];
    }
}

// Final: combine SPLIT=16 float partials per batch in double (fixed order),
// divide, write reversed output. Coalesced float2 reads.
__global__ __launch_bounds__(256)
void hough_final(const float* __restrict__ psy,
                 const float* __restrict__ psx,
                 const float* __restrict__ psw,
                 float* __restrict__ out)
{
    const int t = threadIdx.x;
    const int bb = t >> 3;
    const int l8 = t & 7;
    const int k = bb * SPLIT + l8 * 2;          // == t*2: coalesced float2

    const float2 vy = *(const float2*)(psy + k);
    const float2 vx = *(const float2*)(psx + k);
    const float2 vw = *(const float2*)(psw + k);
    double sy = (double)vy.x + (double)vy.y;
    double sx = (double)vx.x + (double)vx.y;
    double sw = (double)vw.x + (double)vw.y;
    #pragma unroll
    for (int off = 1; off < 8; off <<= 1) {
        sy += __shfl_xor(sy, off);
        sx += __shfl_xor(sx, off);
        sw += __shfl_xor(sw, off);
    }
    if (l8 == 0) {
        // weighted_mean = (sy/sw, sx/sw) in (row, col); output is [::-1]
        out[bb * 2 + 0] = (float)(sx / sw);
        out[bb * 2 + 1] = (float)(sy / sw);
    }
}

extern "C" void kernel_launch(void* const* d_in, const int* in_sizes, int n_in,
                              void* d_out, int out_size, void* d_ws, size_t ws_size,
                              hipStream_t stream)
{
    const float* uv   = (const float*)d_in[0];   // (B, 2, 224, 224) f32
    const int*   pts  = (const int*)d_in[1];     // (B, 4096, 2) i32
    const int*   pair = (const int*)d_in[2];     // (B, 256, 2) i32
    float* out = (float*)d_out;                  // (B, 2) f32
    char* ws = (char*)d_ws;

    float* psy = (float*)(ws + WS_SY_OFF);
    float* psx = (float*)(ws + WS_SX_OFF);
    float* psw = (float*)(ws + WS_SW_OFF);

    hough_fused<<<NBLK, 256, 0, stream>>>(uv, pts, pair, psy, psx, psw);
    hough_final<<<1, 256, 0, stream>>>(psy, psx, psw, out);
}